// Round 4
// baseline (446.990 us; speedup 1.0000x reference)
//
#include <hip/hip_runtime.h>

#define BSZ 4
#define CIN 64
#define HH 128
#define WW 128
#define OCH 64
#define HWSZ (HH*WW)
#define KK 9
#define NPIX (BSZ*HH*WW)

typedef __attribute__((ext_vector_type(8))) short short8v;
typedef __attribute__((ext_vector_type(4))) float float4v;

// ws layout (float offsets)
#define Y_OFF     0
#define OFFS_OFF  (BSZ*OCH*HWSZ)                 // 4194304; offsets: 4*18*16384 = 1179648 floats
#define WOFFT_OFF (OFFS_OFF + BSZ*18*HWSZ)       // 5373952; 10368 floats
#define WTB_OFF   (WOFFT_OFF + 576*18)           // 5384320; 36864 bf16 shorts = 18432 float slots
#define STATS_OFF (WTB_OFF + 18432)              // 5402752; gsum[64] gsq[64] ss[128]

__device__ __forceinline__ short f2bf(float f) {
    unsigned u = __builtin_bit_cast(unsigned, f);
    unsigned r = (u + 0x7FFFu + ((u >> 16) & 1u)) >> 16;
    return (short)r;
}

// ---------------- kernel 0: weight prep (transpose + bf16) ----------------
__global__ void prep_w(const float* __restrict__ w_def,
                       const float* __restrict__ w_off,
                       short* __restrict__ wtb,      // [k][oc][c] bf16
                       float* __restrict__ wofft) {  // [c*9+tap][18]
    int i = blockIdx.x * 256 + threadIdx.x;
    if (i < 36864) {
        int oc = i / 576, rr = i % 576;
        int c = rr / 9, k = rr % 9;
        wtb[(k * OCH + oc) * CIN + c] = f2bf(w_def[i]);
    } else if (i < 36864 + 10368) {
        int j = i - 36864;
        int oc = j / 576, rr = j % 576;
        wofft[rr * 18 + oc] = w_off[j];
    }
}

// ---------------- kernel 1: 3x3 offset conv ----------------
__global__ __launch_bounds__(256) void offset_conv(
    const float* __restrict__ x,
    const float* __restrict__ b_off,
    const float* __restrict__ wofft,
    float* __restrict__ offs)   // [b][ho][18][wo]
{
    const int tid = threadIdx.x;
    const int r = blockIdx.x;
    const int b = r >> 7, ho = r & 127;
    const int wo = tid & 127;
    const int og = __builtin_amdgcn_readfirstlane(tid >> 7); // wave-uniform 0/1

    float oacc[9];
    #pragma unroll
    for (int j = 0; j < 9; ++j) oacc[j] = b_off[og * 9 + j];
    const float* xb = x + b * CIN * HWSZ;
    for (int c = 0; c < CIN; ++c) {
        const float* xc = xb + c * HWSZ;
        #pragma unroll
        for (int kh = 0; kh < 3; ++kh) {
            int yy = ho - 1 + kh;
            int vy = ((unsigned)yy < (unsigned)HH);
            #pragma unroll
            for (int kw = 0; kw < 3; ++kw) {
                int xx = wo - 1 + kw;
                float xv = (vy && ((unsigned)xx < (unsigned)WW)) ? xc[yy * WW + xx] : 0.f;
                const float* wp = wofft + (c * 9 + kh * 3 + kw) * 18 + og * 9;
                #pragma unroll
                for (int j = 0; j < 9; ++j) oacc[j] = fmaf(xv, wp[j], oacc[j]);
            }
        }
    }
    float* orow = offs + (b * HH + ho) * 18 * WW;
    #pragma unroll
    for (int j = 0; j < 9; ++j) orow[(og * 9 + j) * WW + wo] = oacc[j];
}

// ---------------- kernel 2: deform conv via MFMA, zero LDS ----------------
__global__ __launch_bounds__(256) void deform_mfma(
    const float* __restrict__ x,
    const float* __restrict__ offs,
    const short* __restrict__ wtb,
    const float* __restrict__ b_def,
    float* __restrict__ ybuf,
    float* __restrict__ gsum,
    float* __restrict__ gsq)
{
    const int tid  = threadIdx.x;
    const int lane = tid & 63;
    const int wv   = tid >> 6;          // wave 0..3 -> pixel strip
    const int r    = blockIdx.x;
    const int b    = r >> 7, ho = r & 127;
    const int pbase = wv * 32;
    const int l15 = lane & 15;
    const int l4  = lane >> 4;          // 0..3
    const int cbase = l4 * 8;           // this lane's k-slice within a 32-chunk

    float4v acc[4][2];                  // [mt(oc)][nt(pix)]
    #pragma unroll
    for (int mt = 0; mt < 4; ++mt)
        #pragma unroll
        for (int nt = 0; nt < 2; ++nt)
            acc[mt][nt] = (float4v){0.f, 0.f, 0.f, 0.f};

    const float* offrow = offs + (b * HH + ho) * 18 * WW;
    const float* xb = x + b * CIN * HWSZ;

    for (int k = 0; k < KK; ++k) {
        short8v Bf[2][2];               // [nt][kc]
        #pragma unroll
        for (int nt = 0; nt < 2; ++nt) {
            const int p = pbase + nt * 16 + l15;
            float dy = offrow[(2 * k) * WW + p];
            float dx = offrow[(2 * k + 1) * WW + p];
            float py = (float)(ho - 1 + (k / 3)) + dy;
            float px = (float)(p - 1 + (k % 3)) + dx;
            float y0f = floorf(py), x0f = floorf(px);
            int y0 = (int)y0f, x0 = (int)x0f;
            float wy1 = py - y0f, wy0 = 1.f - wy1;
            float wx1 = px - x0f, wx0 = 1.f - wx1;
            int vy0 = ((unsigned)y0 < (unsigned)HH), vy1 = ((unsigned)(y0 + 1) < (unsigned)HH);
            int vx0 = ((unsigned)x0 < (unsigned)WW), vx1 = ((unsigned)(x0 + 1) < (unsigned)WW);
            float w00 = wy0 * wx0 * (float)(vy0 & vx0);
            float w01 = wy0 * wx1 * (float)(vy0 & vx1);
            float w10 = wy1 * wx0 * (float)(vy1 & vx0);
            float w11 = wy1 * wx1 * (float)(vy1 & vx1);
            int y0c = min(max(y0, 0), HH - 1), y1c = min(max(y0 + 1, 0), HH - 1);
            int x0c = min(max(x0, 0), WW - 1), x1c = min(max(x0 + 1, 0), WW - 1);
            int i00 = y0c * WW + x0c, i01 = y0c * WW + x1c;
            int i10 = y1c * WW + x0c, i11 = y1c * WW + x1c;
            #pragma unroll
            for (int kc = 0; kc < 2; ++kc) {
                const float* xc = xb + (kc * 32 + cbase) * HWSZ;
                short8v bf;
                #pragma unroll
                for (int j = 0; j < 8; ++j) {
                    float v = xc[i00] * w00;
                    v = fmaf(xc[i01], w01, v);
                    v = fmaf(xc[i10], w10, v);
                    v = fmaf(xc[i11], w11, v);
                    bf[j] = f2bf(v);
                    xc += HWSZ;
                }
                Bf[nt][kc] = bf;
            }
        }
        // A fragments (weights) straight from L2 + MFMA
        const short* wk = wtb + k * OCH * CIN;
        #pragma unroll
        for (int mt = 0; mt < 4; ++mt) {
            const short* wrow = wk + (mt * 16 + l15) * CIN + cbase;
            #pragma unroll
            for (int kc = 0; kc < 2; ++kc) {
                short8v Af = *(const short8v*)(wrow + kc * 32);
                #pragma unroll
                for (int nt = 0; nt < 2; ++nt)
                    acc[mt][nt] = __builtin_amdgcn_mfma_f32_16x16x32_bf16(Af, Bf[nt][kc], acc[mt][nt], 0, 0, 0);
            }
        }
    }

    // ---- epilogue: bias, y store, BN stats ----
    // C/D layout: col(pix) = lane&15, row(oc) = (lane>>4)*4 + reg
    float lsum[4][4], lsq[4][4];        // [mt][reg]
    #pragma unroll
    for (int mt = 0; mt < 4; ++mt)
        #pragma unroll
        for (int rr = 0; rr < 4; ++rr) { lsum[mt][rr] = 0.f; lsq[mt][rr] = 0.f; }

    const int yrow = ho * WW;
    #pragma unroll
    for (int mt = 0; mt < 4; ++mt) {
        #pragma unroll
        for (int rr = 0; rr < 4; ++rr) {
            const int oc = mt * 16 + l4 * 4 + rr;
            const float bd = b_def[oc];
            float* ydst = ybuf + (b * OCH + oc) * HWSZ + yrow;
            #pragma unroll
            for (int nt = 0; nt < 2; ++nt) {
                const int pix = pbase + nt * 16 + l15;
                float v = acc[mt][nt][rr] + bd;
                ydst[pix] = v;
                lsum[mt][rr] += v;
                lsq[mt][rr]  += v * v;
            }
        }
    }
    // reduce over the 16 pixel-lanes (lane&15)
    #pragma unroll
    for (int m = 1; m <= 8; m <<= 1) {
        #pragma unroll
        for (int mt = 0; mt < 4; ++mt)
            #pragma unroll
            for (int rr = 0; rr < 4; ++rr) {
                lsum[mt][rr] += __shfl_xor(lsum[mt][rr], m);
                lsq[mt][rr]  += __shfl_xor(lsq[mt][rr], m);
            }
    }
    if (l15 == 0) {
        #pragma unroll
        for (int mt = 0; mt < 4; ++mt)
            #pragma unroll
            for (int rr = 0; rr < 4; ++rr) {
                const int oc = mt * 16 + l4 * 4 + rr;
                atomicAdd(&gsum[oc], lsum[mt][rr]);
                atomicAdd(&gsq[oc],  lsq[mt][rr]);
            }
    }
}

// ---------------- kernel 3: BN stats finalize ----------------
__global__ void finalize_bn(const float* __restrict__ gsum, const float* __restrict__ gsq,
                            const float* __restrict__ gamma, const float* __restrict__ beta,
                            float* __restrict__ ss) {
    int c = threadIdx.x;
    if (c < OCH) {
        const float inv = 1.f / (float)NPIX;
        float mean = gsum[c] * inv;
        float var = gsq[c] * inv - mean * mean;
        float rstd = rsqrtf(var + 1e-5f);
        float sc = gamma[c] * rstd;
        ss[c] = sc;
        ss[OCH + c] = beta[c] - mean * sc;
    }
}

// ---------------- kernel 4: BN apply + PReLU ----------------
__global__ __launch_bounds__(256) void apply_bn(const float* __restrict__ ybuf,
                                                const float* __restrict__ ss,
                                                const float* __restrict__ prelu,
                                                float* __restrict__ out) {
    int i = blockIdx.x * 256 + threadIdx.x;       // float4 index, exact grid
    int oc = ((i * 4) >> 14) & 63;
    float sc = ss[oc], sh = ss[OCH + oc], pw = prelu[oc];
    float4 v = ((const float4*)ybuf)[i];
    float t;
    t = fmaf(v.x, sc, sh); v.x = t >= 0.f ? t : pw * t;
    t = fmaf(v.y, sc, sh); v.y = t >= 0.f ? t : pw * t;
    t = fmaf(v.z, sc, sh); v.z = t >= 0.f ? t : pw * t;
    t = fmaf(v.w, sc, sh); v.w = t >= 0.f ? t : pw * t;
    ((float4*)out)[i] = v;
}

extern "C" void kernel_launch(void* const* d_in, const int* in_sizes, int n_in,
                              void* d_out, int out_size, void* d_ws, size_t ws_size,
                              hipStream_t stream) {
    const float* x      = (const float*)d_in[0];
    const float* w_off  = (const float*)d_in[1];
    const float* b_off  = (const float*)d_in[2];
    const float* w_def  = (const float*)d_in[3];
    const float* b_def  = (const float*)d_in[4];
    const float* gamma  = (const float*)d_in[5];
    const float* beta   = (const float*)d_in[6];
    const float* prelu  = (const float*)d_in[7];

    float* ws    = (float*)d_ws;
    float* ybuf  = ws + Y_OFF;
    float* offs  = ws + OFFS_OFF;
    float* wofft = ws + WOFFT_OFF;
    short* wtb   = (short*)(ws + WTB_OFF);
    float* stats = ws + STATS_OFF;
    float* gsum  = stats;
    float* gsq   = stats + OCH;
    float* ss    = stats + 2 * OCH;

    hipMemsetAsync(stats, 0, 2 * OCH * sizeof(float), stream);
    prep_w<<<185, 256, 0, stream>>>(w_def, w_off, wtb, wofft);
    offset_conv<<<BSZ * HH, 256, 0, stream>>>(x, b_off, wofft, offs);
    deform_mfma<<<BSZ * HH, 256, 0, stream>>>(x, offs, wtb, b_def, ybuf, gsum, gsq);
    finalize_bn<<<1, 64, 0, stream>>>(gsum, gsq, gamma, beta, ss);
    apply_bn<<<(BSZ * OCH * HWSZ) / 4 / 256, 256, 0, stream>>>(ybuf, ss, prelu, (float*)d_out);
}

// Round 7
// 268.291 us; speedup vs baseline: 1.6661x; 1.6661x over previous
//
#include <hip/hip_runtime.h>

#define BSZ 4
#define CIN 64
#define HH 128
#define WW 128
#define OCH 64
#define HWSZ (HH*WW)
#define KK 9
#define NPIX (BSZ*HH*WW)

typedef __attribute__((ext_vector_type(8))) short short8v;
typedef __attribute__((ext_vector_type(4))) float float4v;

// ws layout (float offsets)
#define Y_OFF     0
#define OFFS_OFF  (BSZ*OCH*HWSZ)                 // 4194304; 4*18*16384 = 1179648 floats
#define WOFF2_OFF (OFFS_OFF + BSZ*18*HWSZ)       // 5373952; 10368 floats
#define WTB_OFF   (WOFF2_OFF + 576*18)           // 5384320; 36864 bf16 = 18432 float slots
#define STATS_OFF (WTB_OFF + 18432)              // 5402752; gsum[64] gsq[64] ss[128]

__device__ __forceinline__ short f2bf(float f) {
    unsigned u = __builtin_bit_cast(unsigned, f);
    unsigned r = (u + 0x7FFFu + ((u >> 16) & 1u)) >> 16;
    return (short)r;
}

// ---------------- kernel 0: weight prep ----------------
__global__ void prep_w(const float* __restrict__ w_def,
                       const float* __restrict__ w_off,
                       short* __restrict__ wtb,      // [k][oc][c] bf16
                       float* __restrict__ wof2) {   // [tap][c][18]
    int i = blockIdx.x * 256 + threadIdx.x;
    if (i < 36864) {
        int oc = i / 576, rr = i % 576;
        int c = rr / 9, k = rr % 9;
        wtb[(k * OCH + oc) * CIN + c] = f2bf(w_def[i]);
    } else if (i < 36864 + 10368) {
        int j = i - 36864;
        int o = j / 576, rr = j % 576;
        int c = rr / 9, tap = rr % 9;
        wof2[(tap * CIN + c) * 18 + o] = w_off[j];
    }
}

// ---------------- kernel 1: x NCHW -> NHWC (into d_out scratch) ----------------
__global__ __launch_bounds__(256) void transpose_x(const float* __restrict__ x,
                                                   float* __restrict__ xt) {
    int gp = blockIdx.x * 256 + threadIdx.x;   // 0..65535 (b*16384+hw)
    int b = gp >> 14, hw = gp & 16383;
    const float* src = x + b * CIN * HWSZ + hw;
    float* dst = xt + gp * 64;
    #pragma unroll
    for (int c = 0; c < 64; c += 4) {
        float4 v;
        v.x = src[(c + 0) * HWSZ];
        v.y = src[(c + 1) * HWSZ];
        v.z = src[(c + 2) * HWSZ];
        v.w = src[(c + 3) * HWSZ];
        *(float4*)(dst + c) = v;
    }
}

// ---------------- kernel 2: 3x3 offset conv (NHWC reads) ----------------
__global__ __launch_bounds__(256) void offset_conv(
    const float* __restrict__ xt,
    const float* __restrict__ b_off,
    const float* __restrict__ wof2,
    float* __restrict__ offs)   // [b][ho][18][wo]
{
    const int tid = threadIdx.x;
    const int r = blockIdx.x;
    const int b = r >> 7, ho = r & 127;
    const int wo = tid & 127;
    const int og = __builtin_amdgcn_readfirstlane(tid >> 7); // wave-uniform 0/1

    float oacc[9];
    #pragma unroll
    for (int j = 0; j < 9; ++j) oacc[j] = b_off[og * 9 + j];
    const float* xb = xt + b * HWSZ * 64;

    #pragma unroll
    for (int tap = 0; tap < 9; ++tap) {
        const int kh = tap / 3, kw = tap % 3;
        const int yy = ho - 1 + kh;
        const int xx = wo - 1 + kw;
        if (((unsigned)yy < (unsigned)HH) & ((unsigned)xx < (unsigned)WW)) {
            const float* pv = xb + (yy * WW + xx) * 64;
            const float* wp = wof2 + tap * CIN * 18 + og * 9;
            #pragma unroll 4
            for (int c4 = 0; c4 < 16; ++c4) {
                float4 xv = *(const float4*)(pv + c4 * 4);
                #pragma unroll
                for (int cc = 0; cc < 4; ++cc) {
                    const float* w = wp + (c4 * 4 + cc) * 18;
                    float xs = (cc == 0) ? xv.x : (cc == 1) ? xv.y : (cc == 2) ? xv.z : xv.w;
                    #pragma unroll
                    for (int j = 0; j < 9; ++j) oacc[j] = fmaf(xs, w[j], oacc[j]);
                }
            }
        }
    }
    float* orow = offs + (b * HH + ho) * 18 * WW;
    #pragma unroll
    for (int j = 0; j < 9; ++j) orow[(og * 9 + j) * WW + wo] = oacc[j];
}

// ---------------- kernel 3: deform conv via MFMA (NHWC gathers) ----------------
__global__ __launch_bounds__(256, 4) void deform_mfma(
    const float* __restrict__ xt,     // NHWC
    const float* __restrict__ offs,
    const short* __restrict__ wtb,
    const float* __restrict__ b_def,
    float* __restrict__ ybuf,
    float* __restrict__ gsum,
    float* __restrict__ gsq)
{
    __shared__ float red0[4][64];
    __shared__ float red1[4][64];

    const int tid  = threadIdx.x;
    const int lane = tid & 63;
    const int wv   = tid >> 6;
    const int r    = blockIdx.x;           // 1024 blocks
    const int b    = r >> 8;
    const int rem  = r & 255;
    const int ho   = rem >> 1, half = rem & 1;
    const int l15  = lane & 15;
    const int l4   = lane >> 4;
    const int cbase = l4 * 8;
    const int p    = half * 64 + wv * 16 + l15;   // this lane's pixel

    float4v acc[4];
    #pragma unroll
    for (int mt = 0; mt < 4; ++mt) acc[mt] = (float4v){0.f, 0.f, 0.f, 0.f};

    const float* offrow = offs + (b * HH + ho) * 18 * WW;
    const float* xb = xt + b * HWSZ * 64;

    for (int k = 0; k < KK; ++k) {
        float dy = offrow[(2 * k) * WW + p];
        float dx = offrow[(2 * k + 1) * WW + p];
        float py = (float)(ho - 1 + (k / 3)) + dy;
        float px = (float)(p - 1 + (k % 3)) + dx;
        float y0f = floorf(py), x0f = floorf(px);
        int y0 = (int)y0f, x0 = (int)x0f;
        float wy1 = py - y0f, wy0 = 1.f - wy1;
        float wx1 = px - x0f, wx0 = 1.f - wx1;
        int vy0 = ((unsigned)y0 < (unsigned)HH), vy1 = ((unsigned)(y0 + 1) < (unsigned)HH);
        int vx0 = ((unsigned)x0 < (unsigned)WW), vx1 = ((unsigned)(x0 + 1) < (unsigned)WW);
        float w00 = wy0 * wx0 * (float)(vy0 & vx0);
        float w01 = wy0 * wx1 * (float)(vy0 & vx1);
        float w10 = wy1 * wx0 * (float)(vy1 & vx0);
        float w11 = wy1 * wx1 * (float)(vy1 & vx1);
        int y0c = min(max(y0, 0), HH - 1), y1c = min(max(y0 + 1, 0), HH - 1);
        int x0c = min(max(x0, 0), WW - 1), x1c = min(max(x0 + 1, 0), WW - 1);
        const float* p00 = xb + (y0c * WW + x0c) * 64;
        const float* p01 = xb + (y0c * WW + x1c) * 64;
        const float* p10 = xb + (y1c * WW + x0c) * 64;
        const float* p11 = xb + (y1c * WW + x1c) * 64;

        short8v Bf[2];
        #pragma unroll
        for (int kc = 0; kc < 2; ++kc) {
            const int co = kc * 32 + cbase;
            float4 a00 = *(const float4*)(p00 + co), b00 = *(const float4*)(p00 + co + 4);
            float4 a01 = *(const float4*)(p01 + co), b01 = *(const float4*)(p01 + co + 4);
            float4 a10 = *(const float4*)(p10 + co), b10 = *(const float4*)(p10 + co + 4);
            float4 a11 = *(const float4*)(p11 + co), b11 = *(const float4*)(p11 + co + 4);
            float v0 = a00.x * w00 + a01.x * w01 + a10.x * w10 + a11.x * w11;
            float v1 = a00.y * w00 + a01.y * w01 + a10.y * w10 + a11.y * w11;
            float v2 = a00.z * w00 + a01.z * w01 + a10.z * w10 + a11.z * w11;
            float v3 = a00.w * w00 + a01.w * w01 + a10.w * w10 + a11.w * w11;
            float v4 = b00.x * w00 + b01.x * w01 + b10.x * w10 + b11.x * w11;
            float v5 = b00.y * w00 + b01.y * w01 + b10.y * w10 + b11.y * w11;
            float v6 = b00.z * w00 + b01.z * w01 + b10.z * w10 + b11.z * w11;
            float v7 = b00.w * w00 + b01.w * w01 + b10.w * w10 + b11.w * w11;
            short8v bf;
            bf[0] = f2bf(v0); bf[1] = f2bf(v1); bf[2] = f2bf(v2); bf[3] = f2bf(v3);
            bf[4] = f2bf(v4); bf[5] = f2bf(v5); bf[6] = f2bf(v6); bf[7] = f2bf(v7);
            Bf[kc] = bf;
        }

        const short* wk = wtb + k * OCH * CIN;
        #pragma unroll
        for (int mt = 0; mt < 4; ++mt) {
            const short* wrow = wk + (mt * 16 + l15) * CIN + cbase;
            #pragma unroll
            for (int kc = 0; kc < 2; ++kc) {
                short8v Af = *(const short8v*)(wrow + kc * 32);
                acc[mt] = __builtin_amdgcn_mfma_f32_16x16x32_bf16(Af, Bf[kc], acc[mt], 0, 0, 0);
            }
        }
    }

    // ---- epilogue: bias, y store, BN partials ----
    // C/D layout: col(pix)=lane&15, row(oc)=(lane>>4)*4+reg
    float lsum[4][4], lsq[4][4];
    const int yrow = ho * WW;
    #pragma unroll
    for (int mt = 0; mt < 4; ++mt) {
        #pragma unroll
        for (int rr = 0; rr < 4; ++rr) {
            const int oc = mt * 16 + l4 * 4 + rr;
            float v = acc[mt][rr] + b_def[oc];
            ybuf[(b * OCH + oc) * HWSZ + yrow + p] = v;
            lsum[mt][rr] = v;
            lsq[mt][rr]  = v * v;
        }
    }
    #pragma unroll
    for (int m = 1; m <= 8; m <<= 1) {
        #pragma unroll
        for (int mt = 0; mt < 4; ++mt)
            #pragma unroll
            for (int rr = 0; rr < 4; ++rr) {
                lsum[mt][rr] += __shfl_xor(lsum[mt][rr], m);
                lsq[mt][rr]  += __shfl_xor(lsq[mt][rr], m);
            }
    }
    if (l15 == 0) {
        #pragma unroll
        for (int mt = 0; mt < 4; ++mt)
            #pragma unroll
            for (int rr = 0; rr < 4; ++rr) {
                const int oc = mt * 16 + l4 * 4 + rr;
                red0[wv][oc] = lsum[mt][rr];
                red1[wv][oc] = lsq[mt][rr];
            }
    }
    __syncthreads();
    if (tid < 128) {
        const int oc = tid & 63, s = tid >> 6;
        if (s == 0) {
            float v = red0[0][oc] + red0[1][oc] + red0[2][oc] + red0[3][oc];
            atomicAdd(&gsum[oc], v);
        } else {
            float v = red1[0][oc] + red1[1][oc] + red1[2][oc] + red1[3][oc];
            atomicAdd(&gsq[oc], v);
        }
    }
}

// ---------------- kernel 4: BN stats finalize ----------------
__global__ void finalize_bn(const float* __restrict__ gsum, const float* __restrict__ gsq,
                            const float* __restrict__ gamma, const float* __restrict__ beta,
                            float* __restrict__ ss) {
    int c = threadIdx.x;
    if (c < OCH) {
        const float inv = 1.f / (float)NPIX;
        float mean = gsum[c] * inv;
        float var = gsq[c] * inv - mean * mean;
        float rstd = rsqrtf(var + 1e-5f);
        float sc = gamma[c] * rstd;
        ss[c] = sc;
        ss[OCH + c] = beta[c] - mean * sc;
    }
}

// ---------------- kernel 5: BN apply + PReLU ----------------
__global__ __launch_bounds__(256) void apply_bn(const float* __restrict__ ybuf,
                                                const float* __restrict__ ss,
                                                const float* __restrict__ prelu,
                                                float* __restrict__ out) {
    int i = blockIdx.x * 256 + threadIdx.x;       // float4 index, exact grid
    int oc = ((i * 4) >> 14) & 63;
    float sc = ss[oc], sh = ss[OCH + oc], pw = prelu[oc];
    float4 v = ((const float4*)ybuf)[i];
    float t;
    t = fmaf(v.x, sc, sh); v.x = t >= 0.f ? t : pw * t;
    t = fmaf(v.y, sc, sh); v.y = t >= 0.f ? t : pw * t;
    t = fmaf(v.z, sc, sh); v.z = t >= 0.f ? t : pw * t;
    t = fmaf(v.w, sc, sh); v.w = t >= 0.f ? t : pw * t;
    ((float4*)out)[i] = v;
}

extern "C" void kernel_launch(void* const* d_in, const int* in_sizes, int n_in,
                              void* d_out, int out_size, void* d_ws, size_t ws_size,
                              hipStream_t stream) {
    const float* x      = (const float*)d_in[0];
    const float* w_off  = (const float*)d_in[1];
    const float* b_off  = (const float*)d_in[2];
    const float* w_def  = (const float*)d_in[3];
    const float* b_def  = (const float*)d_in[4];
    const float* gamma  = (const float*)d_in[5];
    const float* beta   = (const float*)d_in[6];
    const float* prelu  = (const float*)d_in[7];

    float* ws    = (float*)d_ws;
    float* ybuf  = ws + Y_OFF;
    float* offs  = ws + OFFS_OFF;
    float* wof2  = ws + WOFF2_OFF;
    short* wtb   = (short*)(ws + WTB_OFF);
    float* stats = ws + STATS_OFF;
    float* gsum  = stats;
    float* gsq   = stats + OCH;
    float* ss    = stats + 2 * OCH;

    // xt (NHWC x) lives in d_out: dead by the time apply_bn rewrites it.
    float* xt = (float*)d_out;

    hipMemsetAsync(stats, 0, 2 * OCH * sizeof(float), stream);
    prep_w<<<185, 256, 0, stream>>>(w_def, w_off, wtb, wof2);
    transpose_x<<<BSZ * HWSZ / 256, 256, 0, stream>>>(x, xt);
    offset_conv<<<BSZ * HH, 256, 0, stream>>>(xt, b_off, wof2, offs);
    deform_mfma<<<BSZ * HH * 2, 256, 0, stream>>>(xt, offs, wtb, b_def, ybuf, gsum, gsq);
    finalize_bn<<<1, 64, 0, stream>>>(gsum, gsq, gamma, beta, ss);
    apply_bn<<<(BSZ * OCH * HWSZ) / 4 / 256, 256, 0, stream>>>(ybuf, ss, prelu, (float*)d_out);
}